// Round 9
// baseline (107.020 us; speedup 1.0000x reference)
//
#include <hip/hip_runtime.h>
#include <stdint.h>

typedef short s16x8 __attribute__((ext_vector_type(8)));
typedef unsigned short u16x8 __attribute__((ext_vector_type(8)));
typedef float f32x4 __attribute__((ext_vector_type(4)));

#define XPAD_BYTES ((size_t)(32 * 58 * 58 * 128) * 2)

// xpad layout: [n][row 0..57][cseg 0..15][col 0..57][8c]  (16B chunk = 8 c's)
// wq   layout: [kk 0..8][cseg 0..15][o 0..255][8c]

static __device__ __forceinline__ unsigned short f2bf(float f) {
    union { float f; uint32_t u; } v; v.f = f;
    uint32_t r = v.u + 0x7FFFu + ((v.u >> 16) & 1u);
    return (unsigned short)(r >> 16);
}

static __device__ __forceinline__ s16x8 ldfrag(const unsigned short* p) {
    return *(const s16x8*)p;
}

static __device__ __forceinline__ void gload16(const unsigned short* g, unsigned short* l) {
    __builtin_amdgcn_global_load_lds(
        (const __attribute__((address_space(1))) uint32_t*)g,
        (__attribute__((address_space(3))) uint32_t*)l, 16, 0, 0);
}

// ---------------- weight quantization -> [kk][cseg][o][8] ----------------
__global__ void quant_k(const float* __restrict__ pc,
                        const float* __restrict__ ql,
                        unsigned short* __restrict__ wq) {
    int p = blockIdx.x * 256 + threadIdx.x;
    if (p >= 9 * 16 * 256 * 8) return;
    int j = p & 7;
    int o = (p >> 3) & 255;
    int cs = (p >> 11) & 15;
    int kk = p >> 15;
    int c = cs * 8 + j;
    const float* v = pc + ((size_t)((o * 128 + c) * 9 + kk) * 7);
    float vv[7];
    float s = 0.f;
#pragma unroll
    for (int l = 0; l < 7; ++l) { vv[l] = v[l]; s += vv[l] * vv[l]; }
    float norm = sqrtf(s);
    float best = 10.0f * (vv[0] / norm);
    int bi = 0;
#pragma unroll
    for (int l = 1; l < 7; ++l) {
        float t = 10.0f * (vv[l] / norm);
        if (t > best) { best = t; bi = l; }
    }
    wq[p] = f2bf(ql[bi]);
}

// ---------------- zero the halo border of xpad ----------------
__global__ void border_k(unsigned short* __restrict__ xpad) {
    int i = blockIdx.x * 256 + threadIdx.x;   // 456*256 = 116736 = 32*3648
    const u16x8 z = (u16x8){0, 0, 0, 0, 0, 0, 0, 0};
    int n = i / 3648;
    int rem = i - n * 3648;
    int r, cs, col;
    if (rem < 1856) {
        int rt = rem / 928;
        int q = rem - rt * 928;
        r = rt * 57;
        cs = q / 58;
        col = q - cs * 58;
    } else {
        int rem2 = rem - 1856;
        int ct = rem2 / 896;
        int q = rem2 - ct * 896;
        col = ct * 57;
        cs = q / 56;
        r = 1 + (q - cs * 56);
    }
    *(u16x8*)(xpad + ((((size_t)n * 58 + r) * 16 + cs) * 58 + col) * 8) = z;
}

// ---------------- x: NCHW f32 -> padded [n][row][cseg][col][8] bf16 ----------------
__global__ __launch_bounds__(256) void xform_k(const float* __restrict__ x,
                                               unsigned short* __restrict__ xpad) {
    const int h = blockIdx.x;
    const int n = blockIdx.y;
    const int t = threadIdx.x;
    if (t >= 224) return;
    int cgrp = t / 56;
    int w = t - cgrp * 56;
#pragma unroll
    for (int seg = 0; seg < 4; ++seg) {
        int cs = seg * 4 + cgrp;
        const float* src = x + ((size_t)(n * 128 + cs * 8) * 56 + h) * 56 + w;
        u16x8 d;
#pragma unroll
        for (int jj = 0; jj < 8; ++jj)
            d[jj] = f2bf(src[(size_t)jj * 3136]);
        *(u16x8*)(xpad + ((((size_t)n * 58 + h + 1) * 16 + cs) * 58 + (w + 1)) * 8) = d;
    }
}

// ---------------- implicit-GEMM conv v7 ----------------
// Block: 128 o x (8 rows x 56) = 448 spatial, 512 threads = 8 waves.
// Wave (oh = wave>>2, sq = wave&3): 64 o x 112 spatial.
// LDS: xs [4 cseg][592 pos] 16B single-buffered (37888 B, staged per c-chunk, exposed)
//      wl [2][4 cseg][128 o] 16B double-buffered per tap (16384 B, L2-hot, hidden)
// Total 54272 B -> 2 blocks/CU (16 waves, 4/SIMD). Steady-state compute reads
// ONLY LDS (lgkm); the single in-flight w-prefetch is the only vmem op per phase
// (drained by the phase barrier after ~28 MFMAs of cover). No vmcnt FIFO hazard.
__global__ __launch_bounds__(512, 2) void conv7_k(const unsigned short* __restrict__ xpad,
                                                  const unsigned short* __restrict__ wq,
                                                  float* __restrict__ out) {
    __shared__ __align__(16) unsigned short xs[4 * 592 * 8];    // 37888 B
    __shared__ __align__(16) unsigned short wl[2][512 * 8];     // 16384 B

    const int tid = threadIdx.x;
    const int h0 = blockIdx.x * 8;
    const int n = blockIdx.y;
    const int o0 = blockIdx.z * 128;
    const int lane = tid & 63;
    const int wave = tid >> 6;     // 0..7
    const int oh = wave >> 2;      // 0..1
    const int sq = wave & 3;       // 0..3
    const int l16 = lane & 15;
    const int kgrp = lane >> 4;

    // ---- x staging source offsets (chunk t adds t*1856 elems) ----
    int offx[5];
#pragma unroll
    for (int i = 0; i < 5; ++i) {
        int ci = i * 512 + tid;          // 0..2559
        int ce = ci < 2368 ? ci : 0;
        int cs = ce / 592;               // relative cseg 0..3
        int pos = ce - cs * 592;
        int pe = pos < 580 ? pos : 579;  // clamp pad chunks to valid addr
        int r = pe / 58;
        int col = pe - r * 58;
        offx[i] = (((n * 58 + h0 + r) * 16 + cs) * 58 + col) * 8;
    }
    const bool v4 = wave < 5;            // i=4 covers chunks 2048..2367 (5 waves)

    // ---- w staging: thread -> (cs_rel = tid>>7, o = tid&127) ----
    // source for (t,kk): wq + wsrc + kk*32768 + t*8192 elems
    const int wsrc = ((tid >> 7) * 256 + o0 + (tid & 127)) * 8;

    // ---- B-fragment LDS bases ----
    int bb[7];
#pragma unroll
    for (int f = 0; f < 7; ++f) {
        int s = sq * 112 + f * 16 + l16;     // 0..447
        int r = s / 56;
        int w = s - r * 56;
        bb[f] = (kgrp * 592 + r * 58 + w) * 8;
    }
    // ---- A-fragment LDS base: + of*128 elems per 16-o step ----
    const int ab = (kgrp * 128 + oh * 64 + l16) * 8;

    f32x4 acc[4][7];
#pragma unroll
    for (int a = 0; a < 4; ++a)
#pragma unroll
        for (int f = 0; f < 7; ++f) acc[a][f] = (f32x4){0.f, 0.f, 0.f, 0.f};

    const int wdst = wave * 64 * 8;

    // ---- prologue: stage x(0) and w(0, kk=0) into wl[0] ----
#pragma unroll
    for (int i = 0; i < 4; ++i)
        gload16(xpad + offx[i], &xs[(i * 512 + wave * 64) * 8]);
    if (v4)
        gload16(xpad + offx[4], &xs[(2048 + wave * 64) * 8]);
    gload16(wq + wsrc, &wl[0][wdst]);
    __syncthreads();

#pragma unroll
    for (int t = 0; t < 4; ++t) {
#pragma unroll
        for (int kk = 0; kk < 9; ++kk) {
            const int ph = t * 9 + kk;
            const int cur = ph & 1;

            // issue next w-prefetch (single gload16; L2-hot)
            if (kk < 8)
                gload16(wq + wsrc + (kk + 1) * 32768 + t * 8192, &wl[cur ^ 1][wdst]);
            else if (t < 3)
                gload16(wq + wsrc + (t + 1) * 8192, &wl[cur ^ 1][wdst]);

            s16x8 A0 = ldfrag(&wl[cur][ab]);
            s16x8 A1 = ldfrag(&wl[cur][ab + 128]);
            s16x8 A2 = ldfrag(&wl[cur][ab + 256]);
            s16x8 A3 = ldfrag(&wl[cur][ab + 384]);

            const int kh = kk / 3;
            const int kw = kk - kh * 3;
            const int xo = (kh * 58 + kw) * 8;
#pragma unroll
            for (int f = 0; f < 7; ++f) {
                s16x8 b = ldfrag(&xs[bb[f] + xo]);
                acc[0][f] = __builtin_amdgcn_mfma_f32_16x16x32_bf16(A0, b, acc[0][f], 0, 0, 0);
                acc[1][f] = __builtin_amdgcn_mfma_f32_16x16x32_bf16(A1, b, acc[1][f], 0, 0, 0);
                acc[2][f] = __builtin_amdgcn_mfma_f32_16x16x32_bf16(A2, b, acc[2][f], 0, 0, 0);
                acc[3][f] = __builtin_amdgcn_mfma_f32_16x16x32_bf16(A3, b, acc[3][f], 0, 0, 0);
            }
            __syncthreads();   // waves done with wl[cur]; w-prefetch drained
        }
        // ---- stage x for next c-chunk (xs free: kk=8 barrier passed) ----
        if (t < 3) {
            const int xoff = (t + 1) * 1856;
#pragma unroll
            for (int i = 0; i < 4; ++i)
                gload16(xpad + offx[i] + xoff, &xs[(i * 512 + wave * 64) * 8]);
            if (v4)
                gload16(xpad + offx[4] + xoff, &xs[(2048 + wave * 64) * 8]);
            __syncthreads();   // exposed x-stage drain (4 pulses per kernel)
        }
    }

    // ---- epilogue (mapping verified rounds 1-8) ----
#pragma unroll
    for (int of = 0; of < 4; ++of) {
        int ob = o0 + oh * 64 + of * 16 + kgrp * 4;
#pragma unroll
        for (int f = 0; f < 7; ++f) {
            int s = sq * 112 + f * 16 + l16;
            int r = s / 56;
            int w = s - r * 56;
            int h = h0 + r;
            float* dst = out + ((size_t)(n * 256 + ob) * 56 + h) * 56 + w;
#pragma unroll
            for (int j = 0; j < 4; ++j) dst[(size_t)j * 3136] = acc[of][f][j];
        }
    }
}

extern "C" void kernel_launch(void* const* d_in, const int* in_sizes, int n_in,
                              void* d_out, int out_size, void* d_ws, size_t ws_size,
                              hipStream_t stream) {
    const float* x = (const float*)d_in[0];
    const float* pc = (const float*)d_in[1];
    const float* ql = (const float*)d_in[2];
    float* out = (float*)d_out;

    unsigned short* xpad = (unsigned short*)d_ws;
    unsigned short* wq = (unsigned short*)((char*)d_ws + XPAD_BYTES);

    border_k<<<456, 256, 0, stream>>>(xpad);
    quant_k<<<1152, 256, 0, stream>>>(pc, ql, wq);
    xform_k<<<dim3(56, 32), 256, 0, stream>>>(x, xpad);
    conv7_k<<<dim3(7, 32, 2), 512, 0, stream>>>(xpad, wq, out);
}

// Round 10
// 91.214 us; speedup vs baseline: 1.1733x; 1.1733x over previous
//
#include <hip/hip_runtime.h>
#include <stdint.h>

typedef short s16x8 __attribute__((ext_vector_type(8)));
typedef unsigned short u16x8 __attribute__((ext_vector_type(8)));
typedef float f32x4 __attribute__((ext_vector_type(4)));

#define XPAD_BYTES ((size_t)(32 * 58 * 58 * 128) * 2)

// xpad layout: [n][row 0..57][cseg 0..15][col 0..57][8c]  (16B chunk = 8 c's)
// wq   layout: [kk 0..8][cseg 0..15][o 0..255][8c]

static __device__ __forceinline__ unsigned short f2bf(float f) {
    union { float f; uint32_t u; } v; v.f = f;
    uint32_t r = v.u + 0x7FFFu + ((v.u >> 16) & 1u);
    return (unsigned short)(r >> 16);
}

static __device__ __forceinline__ s16x8 ldfrag(const unsigned short* p) {
    return *(const s16x8*)p;
}

static __device__ __forceinline__ void gload16(const unsigned short* g, unsigned short* l) {
    __builtin_amdgcn_global_load_lds(
        (const __attribute__((address_space(1))) uint32_t*)g,
        (__attribute__((address_space(3))) uint32_t*)l, 16, 0, 0);
}

// ---------------- fused: xpad border zero + weight quantization ----------------
__global__ void prep_k(const float* __restrict__ pc,
                       const float* __restrict__ ql,
                       unsigned short* __restrict__ wq,
                       unsigned short* __restrict__ xpad) {
    int b = blockIdx.x;
    int tid = threadIdx.x;
    if (b < 456) {
        // border zero: 116736 chunks = 32 n * 3648
        int i = b * 256 + tid;
        const u16x8 z = (u16x8){0, 0, 0, 0, 0, 0, 0, 0};
        int n = i / 3648;
        int rem = i - n * 3648;
        int r, cs, col;
        if (rem < 1856) {
            int rt = rem / 928;
            int q = rem - rt * 928;
            r = rt * 57;
            cs = q / 58;
            col = q - cs * 58;
        } else {
            int rem2 = rem - 1856;
            int ct = rem2 / 896;
            int q = rem2 - ct * 896;
            col = ct * 57;
            cs = q / 56;
            r = 1 + (q - cs * 56);
        }
        *(u16x8*)(xpad + ((((size_t)n * 58 + r) * 16 + cs) * 58 + col) * 8) = z;
    } else {
        // quant: p in [0, 9*16*256*8)
        int p = (b - 456) * 256 + tid;
        if (p >= 9 * 16 * 256 * 8) return;
        int j = p & 7;
        int o = (p >> 3) & 255;
        int cs = (p >> 11) & 15;
        int kk = p >> 15;
        int c = cs * 8 + j;
        const float* v = pc + ((size_t)((o * 128 + c) * 9 + kk) * 7);
        float vv[7];
        float s = 0.f;
#pragma unroll
        for (int l = 0; l < 7; ++l) { vv[l] = v[l]; s += vv[l] * vv[l]; }
        float norm = sqrtf(s);
        float best = 10.0f * (vv[0] / norm);
        int bi = 0;
#pragma unroll
        for (int l = 1; l < 7; ++l) {
            float t = 10.0f * (vv[l] / norm);
            if (t > best) { best = t; bi = l; }
        }
        wq[p] = f2bf(ql[bi]);
    }
}

// ---------------- x: NCHW f32 -> padded [n][row][cseg][col][8] bf16 ----------------
__global__ __launch_bounds__(256) void xform_k(const float* __restrict__ x,
                                               unsigned short* __restrict__ xpad) {
    const int h = blockIdx.x;
    const int n = blockIdx.y;
    const int t = threadIdx.x;
    if (t >= 224) return;
    int cgrp = t / 56;
    int w = t - cgrp * 56;
#pragma unroll
    for (int seg = 0; seg < 4; ++seg) {
        int cs = seg * 4 + cgrp;
        const float* src = x + ((size_t)(n * 128 + cs * 8) * 56 + h) * 56 + w;
        u16x8 d;
#pragma unroll
        for (int jj = 0; jj < 8; ++jj)
            d[jj] = f2bf(src[(size_t)jj * 3136]);
        *(u16x8*)(xpad + ((((size_t)n * 58 + h + 1) * 16 + cs) * 58 + (w + 1)) * 8) = d;
    }
}

// ---------------- implicit-GEMM conv v8: max TLP ----------------
// Block: 64 o x (8 rows x 56) = 448 spatial, 256 threads = 4 waves.
// Wave sq: 64 o x 112 spatial (conv5's verified compute loop).
// LDS: xs [4 cseg][592 pos] 16B SINGLE-buffered = 37888 B
//   -> 4 blocks/CU (151552 <= 163840), VGPR 128 -> 16 waves/CU = 4 waves/SIMD.
// Weights: global->reg A-frag prefetch (L2-hot, conv5-verified). During the kk
// compute loop the vmem FIFO holds ONLY A-loads (staging drained at chunk edge).
// Staging is a short exposed pulse per chunk, covered by 3 co-resident blocks.
__global__ __launch_bounds__(256, 2) void conv8_k(const unsigned short* __restrict__ xpad,
                                                  const unsigned short* __restrict__ wq,
                                                  float* __restrict__ out) {
    __shared__ __align__(16) unsigned short xs[4 * 592 * 8];   // 37888 B

    const int tid = threadIdx.x;
    const int h0 = blockIdx.x * 8;
    const int n = blockIdx.y;
    const int o0 = blockIdx.z * 64;
    const int lane = tid & 63;
    const int wave = tid >> 6;     // 0..3 (spatial quarter)
    const int l16 = lane & 15;
    const int kgrp = lane >> 4;

    // ---- x staging source offsets (chunk t adds t*1856 elems) ----
    int offx[10];
#pragma unroll
    for (int i = 0; i < 10; ++i) {
        int ci = i * 256 + tid;          // 0..2559
        int ce = ci < 2368 ? ci : 0;
        int cs = ce / 592;               // relative cseg 0..3
        int pos = ce - cs * 592;
        int pe = pos < 580 ? pos : 579;  // clamp pad chunks to valid addr
        int r = pe / 58;
        int col = pe - r * 58;
        offx[i] = (((n * 58 + h0 + r) * 16 + cs) * 58 + col) * 8;
    }
    const bool v9 = (wave == 0);         // i=9: chunks 2304..2367 only

    // ---- B-fragment LDS bases ----
    int bb[7];
#pragma unroll
    for (int f = 0; f < 7; ++f) {
        int s = wave * 112 + f * 16 + l16;   // 0..447
        int r = s / 56;
        int w = s - r * 56;
        bb[f] = (kgrp * 592 + r * 58 + w) * 8;
    }

    // ---- A-fragment global base: A(kk,t,of) = wA + kk*32768 + t*8192 + of*128 ----
    const unsigned short* wA = wq + (size_t)(kgrp * 256 + o0 + l16) * 8;

    f32x4 acc[4][7];
#pragma unroll
    for (int a = 0; a < 4; ++a)
#pragma unroll
        for (int f = 0; f < 7; ++f) acc[a][f] = (f32x4){0.f, 0.f, 0.f, 0.f};

    // ---- prologue: stage chunk 0 ----
#pragma unroll
    for (int i = 0; i < 9; ++i)
        gload16(xpad + offx[i], &xs[(i * 256 + wave * 64) * 8]);
    if (v9)
        gload16(xpad + offx[9], &xs[(2304 + wave * 64) * 8]);
    __syncthreads();

#pragma unroll
    for (int t = 0; t < 4; ++t) {
        s16x8 A0[4], A1[4];
#pragma unroll
        for (int of = 0; of < 4; ++of)
            A0[of] = ldfrag(wA + t * 8192 + of * 128);

#pragma unroll
        for (int kk = 0; kk < 9; ++kk) {
            s16x8 Ac[4];
#pragma unroll
            for (int of = 0; of < 4; ++of) Ac[of] = (kk & 1) ? A1[of] : A0[of];
            if (kk < 8) {
#pragma unroll
                for (int of = 0; of < 4; ++of) {
                    s16x8 vld = ldfrag(wA + (kk + 1) * 32768 + t * 8192 + of * 128);
                    if (kk & 1) A0[of] = vld; else A1[of] = vld;
                }
            }
            const int kh = kk / 3;
            const int kw = kk - kh * 3;
            const int xo = (kh * 58 + kw) * 8;
#pragma unroll
            for (int f = 0; f < 7; ++f) {
                s16x8 b = ldfrag(&xs[bb[f] + xo]);
                acc[0][f] = __builtin_amdgcn_mfma_f32_16x16x32_bf16(Ac[0], b, acc[0][f], 0, 0, 0);
                acc[1][f] = __builtin_amdgcn_mfma_f32_16x16x32_bf16(Ac[1], b, acc[1][f], 0, 0, 0);
                acc[2][f] = __builtin_amdgcn_mfma_f32_16x16x32_bf16(Ac[2], b, acc[2][f], 0, 0, 0);
                acc[3][f] = __builtin_amdgcn_mfma_f32_16x16x32_bf16(Ac[3], b, acc[3][f], 0, 0, 0);
            }
        }

        // ---- stage next c-chunk (exposed pulse; covered by co-resident blocks) ----
        if (t < 3) {
            __syncthreads();   // all waves done reading xs
            const int xoff = (t + 1) * 1856;
#pragma unroll
            for (int i = 0; i < 9; ++i)
                gload16(xpad + offx[i] + xoff, &xs[(i * 256 + wave * 64) * 8]);
            if (v9)
                gload16(xpad + offx[9] + xoff, &xs[(2304 + wave * 64) * 8]);
            __syncthreads();   // staged data visible; vmem FIFO now empty
        }
    }

    // ---- epilogue (mapping verified rounds 1-9) ----
#pragma unroll
    for (int of = 0; of < 4; ++of) {
        int ob = o0 + of * 16 + kgrp * 4;
#pragma unroll
        for (int f = 0; f < 7; ++f) {
            int s = wave * 112 + f * 16 + l16;
            int r = s / 56;
            int w = s - r * 56;
            int h = h0 + r;
            float* dst = out + ((size_t)(n * 256 + ob) * 56 + h) * 56 + w;
#pragma unroll
            for (int j = 0; j < 4; ++j) dst[(size_t)j * 3136] = acc[of][f][j];
        }
    }
}

extern "C" void kernel_launch(void* const* d_in, const int* in_sizes, int n_in,
                              void* d_out, int out_size, void* d_ws, size_t ws_size,
                              hipStream_t stream) {
    const float* x = (const float*)d_in[0];
    const float* pc = (const float*)d_in[1];
    const float* ql = (const float*)d_in[2];
    float* out = (float*)d_out;

    unsigned short* xpad = (unsigned short*)d_ws;
    unsigned short* wq = (unsigned short*)((char*)d_ws + XPAD_BYTES);

    prep_k<<<456 + 1152, 256, 0, stream>>>(pc, ql, wq, xpad);
    xform_k<<<dim3(56, 32), 256, 0, stream>>>(x, xpad);
    conv8_k<<<dim3(7, 32, 4), 256, 0, stream>>>(xpad, wq, out);
}

// Round 11
// 83.658 us; speedup vs baseline: 1.2793x; 1.0903x over previous
//
#include <hip/hip_runtime.h>
#include <stdint.h>

typedef short s16x8 __attribute__((ext_vector_type(8)));
typedef unsigned short u16x8 __attribute__((ext_vector_type(8)));
typedef float f32x4 __attribute__((ext_vector_type(4)));

#define XPAD_BYTES ((size_t)(32 * 58 * 58 * 128) * 2)

// xpad layout: [n][row 0..57][cseg 0..15][col 0..57][8c]  (16B chunk = 8 c's)
// wq   layout: [kk 0..8][cseg 0..15][o 0..255][8c]

static __device__ __forceinline__ unsigned short f2bf(float f) {
    union { float f; uint32_t u; } v; v.f = f;
    uint32_t r = v.u + 0x7FFFu + ((v.u >> 16) & 1u);
    return (unsigned short)(r >> 16);
}

static __device__ __forceinline__ s16x8 ldfrag(const unsigned short* p) {
    return *(const s16x8*)p;
}

static __device__ __forceinline__ void gload16(const unsigned short* g, unsigned short* l) {
    __builtin_amdgcn_global_load_lds(
        (const __attribute__((address_space(1))) uint32_t*)g,
        (__attribute__((address_space(3))) uint32_t*)l, 16, 0, 0);
}

// ---------------- fused: xpad border zero + weight quantization ----------------
__global__ void prep_k(const float* __restrict__ pc,
                       const float* __restrict__ ql,
                       unsigned short* __restrict__ wq,
                       unsigned short* __restrict__ xpad) {
    int b = blockIdx.x;
    int tid = threadIdx.x;
    if (b < 456) {
        int i = b * 256 + tid;
        const u16x8 z = (u16x8){0, 0, 0, 0, 0, 0, 0, 0};
        int n = i / 3648;
        int rem = i - n * 3648;
        int r, cs, col;
        if (rem < 1856) {
            int rt = rem / 928;
            int q = rem - rt * 928;
            r = rt * 57;
            cs = q / 58;
            col = q - cs * 58;
        } else {
            int rem2 = rem - 1856;
            int ct = rem2 / 896;
            int q = rem2 - ct * 896;
            col = ct * 57;
            cs = q / 56;
            r = 1 + (q - cs * 56);
        }
        *(u16x8*)(xpad + ((((size_t)n * 58 + r) * 16 + cs) * 58 + col) * 8) = z;
    } else {
        int p = (b - 456) * 256 + tid;
        if (p >= 9 * 16 * 256 * 8) return;
        int j = p & 7;
        int o = (p >> 3) & 255;
        int cs = (p >> 11) & 15;
        int kk = p >> 15;
        int c = cs * 8 + j;
        const float* v = pc + ((size_t)((o * 128 + c) * 9 + kk) * 7);
        float vv[7];
        float s = 0.f;
#pragma unroll
        for (int l = 0; l < 7; ++l) { vv[l] = v[l]; s += vv[l] * vv[l]; }
        float norm = sqrtf(s);
        float best = 10.0f * (vv[0] / norm);
        int bi = 0;
#pragma unroll
        for (int l = 1; l < 7; ++l) {
            float t = 10.0f * (vv[l] / norm);
            if (t > best) { best = t; bi = l; }
        }
        wq[p] = f2bf(ql[bi]);
    }
}

// ---------------- x: NCHW f32 -> padded [n][row][cseg][col][8] bf16 ----------------
__global__ __launch_bounds__(256) void xform_k(const float* __restrict__ x,
                                               unsigned short* __restrict__ xpad) {
    const int h = blockIdx.x;
    const int n = blockIdx.y;
    const int t = threadIdx.x;
    if (t >= 224) return;
    int cgrp = t / 56;
    int w = t - cgrp * 56;
#pragma unroll
    for (int seg = 0; seg < 4; ++seg) {
        int cs = seg * 4 + cgrp;
        const float* src = x + ((size_t)(n * 128 + cs * 8) * 56 + h) * 56 + w;
        u16x8 d;
#pragma unroll
        for (int jj = 0; jj < 8; ++jj)
            d[jj] = f2bf(src[(size_t)jj * 3136]);
        *(u16x8*)(xpad + ((((size_t)n * 58 + h + 1) * 16 + cs) * 58 + (w + 1)) * 8) = d;
    }
}

// ---------------- implicit-GEMM conv v9: conv8 + T5 setprio ----------------
// Block: 64 o x (8 rows x 56) = 448 spatial, 256 threads = 4 waves.
// LDS: xs [4 cseg][592 pos] 16B single-buffered = 37888 B.
// T5: setprio(1) around each kk's ds_read+MFMA cluster; staging/A-prefetch at
// prio 0. Waves drift across the 9-kk stretch between barriers (role-split),
// so scheduler can favor MFMA-issuing waves.
__global__ __launch_bounds__(256, 2) void conv9_k(const unsigned short* __restrict__ xpad,
                                                  const unsigned short* __restrict__ wq,
                                                  float* __restrict__ out) {
    __shared__ __align__(16) unsigned short xs[4 * 592 * 8];   // 37888 B

    const int tid = threadIdx.x;
    const int h0 = blockIdx.x * 8;
    const int n = blockIdx.y;
    const int o0 = blockIdx.z * 64;
    const int lane = tid & 63;
    const int wave = tid >> 6;
    const int l16 = lane & 15;
    const int kgrp = lane >> 4;

    int offx[10];
#pragma unroll
    for (int i = 0; i < 10; ++i) {
        int ci = i * 256 + tid;
        int ce = ci < 2368 ? ci : 0;
        int cs = ce / 592;
        int pos = ce - cs * 592;
        int pe = pos < 580 ? pos : 579;
        int r = pe / 58;
        int col = pe - r * 58;
        offx[i] = (((n * 58 + h0 + r) * 16 + cs) * 58 + col) * 8;
    }
    const bool v9 = (wave == 0);

    int bb[7];
#pragma unroll
    for (int f = 0; f < 7; ++f) {
        int s = wave * 112 + f * 16 + l16;
        int r = s / 56;
        int w = s - r * 56;
        bb[f] = (kgrp * 592 + r * 58 + w) * 8;
    }

    const unsigned short* wA = wq + (size_t)(kgrp * 256 + o0 + l16) * 8;

    f32x4 acc[4][7];
#pragma unroll
    for (int a = 0; a < 4; ++a)
#pragma unroll
        for (int f = 0; f < 7; ++f) acc[a][f] = (f32x4){0.f, 0.f, 0.f, 0.f};

#pragma unroll
    for (int i = 0; i < 9; ++i)
        gload16(xpad + offx[i], &xs[(i * 256 + wave * 64) * 8]);
    if (v9)
        gload16(xpad + offx[9], &xs[(2304 + wave * 64) * 8]);
    __syncthreads();

#pragma unroll
    for (int t = 0; t < 4; ++t) {
        s16x8 A0[4], A1[4];
#pragma unroll
        for (int of = 0; of < 4; ++of)
            A0[of] = ldfrag(wA + t * 8192 + of * 128);

#pragma unroll
        for (int kk = 0; kk < 9; ++kk) {
            s16x8 Ac[4];
#pragma unroll
            for (int of = 0; of < 4; ++of) Ac[of] = (kk & 1) ? A1[of] : A0[of];
            if (kk < 8) {
#pragma unroll
                for (int of = 0; of < 4; ++of) {
                    s16x8 vld = ldfrag(wA + (kk + 1) * 32768 + t * 8192 + of * 128);
                    if (kk & 1) A0[of] = vld; else A1[of] = vld;
                }
            }
            const int kh = kk / 3;
            const int kw = kk - kh * 3;
            const int xo = (kh * 58 + kw) * 8;

            __builtin_amdgcn_s_setprio(1);
#pragma unroll
            for (int f = 0; f < 7; ++f) {
                s16x8 b = ldfrag(&xs[bb[f] + xo]);
                acc[0][f] = __builtin_amdgcn_mfma_f32_16x16x32_bf16(Ac[0], b, acc[0][f], 0, 0, 0);
                acc[1][f] = __builtin_amdgcn_mfma_f32_16x16x32_bf16(Ac[1], b, acc[1][f], 0, 0, 0);
                acc[2][f] = __builtin_amdgcn_mfma_f32_16x16x32_bf16(Ac[2], b, acc[2][f], 0, 0, 0);
                acc[3][f] = __builtin_amdgcn_mfma_f32_16x16x32_bf16(Ac[3], b, acc[3][f], 0, 0, 0);
            }
            __builtin_amdgcn_s_setprio(0);
        }

        if (t < 3) {
            __syncthreads();
            const int xoff = (t + 1) * 1856;
#pragma unroll
            for (int i = 0; i < 9; ++i)
                gload16(xpad + offx[i] + xoff, &xs[(i * 256 + wave * 64) * 8]);
            if (v9)
                gload16(xpad + offx[9] + xoff, &xs[(2304 + wave * 64) * 8]);
            __syncthreads();
        }
    }

    // ---- epilogue (mapping verified rounds 1-10) ----
#pragma unroll
    for (int of = 0; of < 4; ++of) {
        int ob = o0 + of * 16 + kgrp * 4;
#pragma unroll
        for (int f = 0; f < 7; ++f) {
            int s = wave * 112 + f * 16 + l16;
            int r = s / 56;
            int w = s - r * 56;
            int h = h0 + r;
            float* dst = out + ((size_t)(n * 256 + ob) * 56 + h) * 56 + w;
#pragma unroll
            for (int j = 0; j < 4; ++j) dst[(size_t)j * 3136] = acc[of][f][j];
        }
    }
}

extern "C" void kernel_launch(void* const* d_in, const int* in_sizes, int n_in,
                              void* d_out, int out_size, void* d_ws, size_t ws_size,
                              hipStream_t stream) {
    const float* x = (const float*)d_in[0];
    const float* pc = (const float*)d_in[1];
    const float* ql = (const float*)d_in[2];
    float* out = (float*)d_out;

    unsigned short* xpad = (unsigned short*)d_ws;
    unsigned short* wq = (unsigned short*)((char*)d_ws + XPAD_BYTES);

    prep_k<<<456 + 1152, 256, 0, stream>>>(pc, ql, wq, xpad);
    xform_k<<<dim3(56, 32), 256, 0, stream>>>(x, xpad);
    conv9_k<<<dim3(7, 32, 4), 256, 0, stream>>>(xpad, wq, out);
}

// Round 12
// 82.308 us; speedup vs baseline: 1.3002x; 1.0164x over previous
//
#include <hip/hip_runtime.h>
#include <stdint.h>

typedef short s16x8 __attribute__((ext_vector_type(8)));
typedef unsigned short u16x8 __attribute__((ext_vector_type(8)));
typedef float f32x4 __attribute__((ext_vector_type(4)));

#define XPAD_BYTES ((size_t)(32 * 58 * 58 * 128) * 2)

// xpad layout: [n][row 0..57][cseg 0..15][col 0..57][8c]  (16B chunk = 8 c's)
// wq   layout: [kk 0..8][cseg 0..15][o 0..255][8c]

static __device__ __forceinline__ unsigned short f2bf(float f) {
    union { float f; uint32_t u; } v; v.f = f;
    uint32_t r = v.u + 0x7FFFu + ((v.u >> 16) & 1u);
    return (unsigned short)(r >> 16);
}

static __device__ __forceinline__ s16x8 ldfrag(const unsigned short* p) {
    return *(const s16x8*)p;
}

static __device__ __forceinline__ void gload16(const unsigned short* g, unsigned short* l) {
    __builtin_amdgcn_global_load_lds(
        (const __attribute__((address_space(1))) uint32_t*)g,
        (__attribute__((address_space(3))) uint32_t*)l, 16, 0, 0);
}

// ---------------- fused: xpad border zero + weight quantization ----------------
__global__ void prep_k(const float* __restrict__ pc,
                       const float* __restrict__ ql,
                       unsigned short* __restrict__ wq,
                       unsigned short* __restrict__ xpad) {
    int b = blockIdx.x;
    int tid = threadIdx.x;
    if (b < 456) {
        int i = b * 256 + tid;
        const u16x8 z = (u16x8){0, 0, 0, 0, 0, 0, 0, 0};
        int n = i / 3648;
        int rem = i - n * 3648;
        int r, cs, col;
        if (rem < 1856) {
            int rt = rem / 928;
            int q = rem - rt * 928;
            r = rt * 57;
            cs = q / 58;
            col = q - cs * 58;
        } else {
            int rem2 = rem - 1856;
            int ct = rem2 / 896;
            int q = rem2 - ct * 896;
            col = ct * 57;
            cs = q / 56;
            r = 1 + (q - cs * 56);
        }
        *(u16x8*)(xpad + ((((size_t)n * 58 + r) * 16 + cs) * 58 + col) * 8) = z;
    } else {
        int p = (b - 456) * 256 + tid;
        if (p >= 9 * 16 * 256 * 8) return;
        int j = p & 7;
        int o = (p >> 3) & 255;
        int cs = (p >> 11) & 15;
        int kk = p >> 15;
        int c = cs * 8 + j;
        const float* v = pc + ((size_t)((o * 128 + c) * 9 + kk) * 7);
        float vv[7];
        float s = 0.f;
#pragma unroll
        for (int l = 0; l < 7; ++l) { vv[l] = v[l]; s += vv[l] * vv[l]; }
        float norm = sqrtf(s);
        float best = 10.0f * (vv[0] / norm);
        int bi = 0;
#pragma unroll
        for (int l = 1; l < 7; ++l) {
            float t = 10.0f * (vv[l] / norm);
            if (t > best) { best = t; bi = l; }
        }
        wq[p] = f2bf(ql[bi]);
    }
}

// ---------------- x: NCHW f32 -> padded [n][row][cseg][col][8] bf16 ----------------
// Thread -> (cs, col): loads coalesced (col-consecutive f32), stores fully
// contiguous 16B chunks (col-consecutive in xpad layout).
__global__ __launch_bounds__(256) void xform_k(const float* __restrict__ x,
                                               unsigned short* __restrict__ xpad) {
    const int h = blockIdx.x;
    const int n = blockIdx.y;
    const int t = threadIdx.x;
#pragma unroll
    for (int it = 0; it < 4; ++it) {
        int idx = it * 256 + t;          // 0..895 = 16 cs * 56 col
        if (idx < 896) {
            int cs = idx / 56;
            int col = idx - cs * 56;
            const float* src = x + ((size_t)(n * 128 + cs * 8) * 56 + h) * 56 + col;
            u16x8 d;
#pragma unroll
            for (int jj = 0; jj < 8; ++jj)
                d[jj] = f2bf(src[(size_t)jj * 3136]);
            *(u16x8*)(xpad + ((((size_t)n * 58 + h + 1) * 16 + cs) * 58 + (col + 1)) * 8) = d;
        }
    }
}

// ---------------- implicit-GEMM conv v10: all-resident small blocks + T5 ----------------
// Block: 64 o x (4 rows x 56) = 224 spatial, 128 threads = 2 waves.
// Wave: 64 o x 112 spatial (conv9's verified compute loop, T5 setprio kept).
// LDS: xs [4 cs][352 pos (348 used)] 16B = 22528 B.
// Grid 14h x 32n x 4o = 1792 = EXACTLY 7 blocks/CU, all co-resident
// (LDS 7x22528 = 157696 <= 163840; VGPR <=128 allows 16 waves >= 14).
// Perfect balance, zero tail, 7 independent phase-shifted blocks hide staging.
__global__ __launch_bounds__(128, 2) void conv10_k(const unsigned short* __restrict__ xpad,
                                                   const unsigned short* __restrict__ wq,
                                                   float* __restrict__ out) {
    __shared__ __align__(16) unsigned short xs[4 * 352 * 8];   // 22528 B

    const int tid = threadIdx.x;
    const int h0 = blockIdx.x * 4;
    const int n = blockIdx.y;
    const int o0 = blockIdx.z * 64;
    const int lane = tid & 63;
    const int wave = tid >> 6;     // 0..1 (spatial half)
    const int l16 = lane & 15;
    const int kgrp = lane >> 4;

    // ---- x staging source offsets: 1408 chunks (4 cs x 352, 348 used) ----
    int offx[11];
#pragma unroll
    for (int i = 0; i < 11; ++i) {
        int ci = i * 128 + tid;          // 0..1407
        int cs = ci / 352;
        int pos = ci - cs * 352;
        int pe = pos < 348 ? pos : 347;  // clamp pad chunks to valid addr
        int r = pe / 58;                 // 0..5 (rows h0-1 .. h0+4 of input)
        int col = pe - r * 58;
        offx[i] = (((n * 58 + h0 + r) * 16 + cs) * 58 + col) * 8;
    }

    // ---- B-fragment LDS bases ----
    int bb[7];
#pragma unroll
    for (int f = 0; f < 7; ++f) {
        int s = wave * 112 + f * 16 + l16;   // 0..223
        int r = s / 56;
        int w = s - r * 56;
        bb[f] = (kgrp * 352 + r * 58 + w) * 8;
    }

    // ---- A-fragment global base: A(kk,t,of) = wA + kk*32768 + t*8192 + of*128 ----
    const unsigned short* wA = wq + (size_t)(kgrp * 256 + o0 + l16) * 8;

    f32x4 acc[4][7];
#pragma unroll
    for (int a = 0; a < 4; ++a)
#pragma unroll
        for (int f = 0; f < 7; ++f) acc[a][f] = (f32x4){0.f, 0.f, 0.f, 0.f};

    // ---- prologue: stage chunk 0 ----
#pragma unroll
    for (int i = 0; i < 11; ++i)
        gload16(xpad + offx[i], &xs[(i * 128 + wave * 64) * 8]);
    __syncthreads();

#pragma unroll
    for (int t = 0; t < 4; ++t) {
        s16x8 A0[4], A1[4];
#pragma unroll
        for (int of = 0; of < 4; ++of)
            A0[of] = ldfrag(wA + t * 8192 + of * 128);

#pragma unroll
        for (int kk = 0; kk < 9; ++kk) {
            s16x8 Ac[4];
#pragma unroll
            for (int of = 0; of < 4; ++of) Ac[of] = (kk & 1) ? A1[of] : A0[of];
            if (kk < 8) {
#pragma unroll
                for (int of = 0; of < 4; ++of) {
                    s16x8 vld = ldfrag(wA + (kk + 1) * 32768 + t * 8192 + of * 128);
                    if (kk & 1) A0[of] = vld; else A1[of] = vld;
                }
            }
            const int kh = kk / 3;
            const int kw = kk - kh * 3;
            const int xo = (kh * 58 + kw) * 8;

            __builtin_amdgcn_s_setprio(1);
#pragma unroll
            for (int f = 0; f < 7; ++f) {
                s16x8 b = ldfrag(&xs[bb[f] + xo]);
                acc[0][f] = __builtin_amdgcn_mfma_f32_16x16x32_bf16(Ac[0], b, acc[0][f], 0, 0, 0);
                acc[1][f] = __builtin_amdgcn_mfma_f32_16x16x32_bf16(Ac[1], b, acc[1][f], 0, 0, 0);
                acc[2][f] = __builtin_amdgcn_mfma_f32_16x16x32_bf16(Ac[2], b, acc[2][f], 0, 0, 0);
                acc[3][f] = __builtin_amdgcn_mfma_f32_16x16x32_bf16(Ac[3], b, acc[3][f], 0, 0, 0);
            }
            __builtin_amdgcn_s_setprio(0);
        }

        if (t < 3) {
            __syncthreads();
            const int xoff = (t + 1) * 1856;
#pragma unroll
            for (int i = 0; i < 11; ++i)
                gload16(xpad + offx[i] + xoff, &xs[(i * 128 + wave * 64) * 8]);
            __syncthreads();
        }
    }

    // ---- epilogue (mapping verified rounds 1-11) ----
#pragma unroll
    for (int of = 0; of < 4; ++of) {
        int ob = o0 + of * 16 + kgrp * 4;
#pragma unroll
        for (int f = 0; f < 7; ++f) {
            int s = wave * 112 + f * 16 + l16;
            int r = s / 56;
            int w = s - r * 56;
            int h = h0 + r;
            float* dst = out + ((size_t)(n * 256 + ob) * 56 + h) * 56 + w;
#pragma unroll
            for (int j = 0; j < 4; ++j) dst[(size_t)j * 3136] = acc[of][f][j];
        }
    }
}

extern "C" void kernel_launch(void* const* d_in, const int* in_sizes, int n_in,
                              void* d_out, int out_size, void* d_ws, size_t ws_size,
                              hipStream_t stream) {
    const float* x = (const float*)d_in[0];
    const float* pc = (const float*)d_in[1];
    const float* ql = (const float*)d_in[2];
    float* out = (float*)d_out;

    unsigned short* xpad = (unsigned short*)d_ws;
    unsigned short* wq = (unsigned short*)((char*)d_ws + XPAD_BYTES);

    prep_k<<<456 + 1152, 256, 0, stream>>>(pc, ql, wq, xpad);
    xform_k<<<dim3(56, 32), 256, 0, stream>>>(x, xpad);
    conv10_k<<<dim3(14, 32, 4), 128, 0, stream>>>(xpad, wq, out);
}